// Round 14
// baseline (994.334 us; speedup 1.0000x reference)
//
#include <hip/hip_runtime.h>

// R14: eliminate G0 materialization (kt_g0, 256 MB round-trip, ~56 µs).
// Insight: G0[i][d][j] = d0_i[j] * gw0[d+1][j] — the weight part is sample-
// independent. B1 now stages the shared 256 KB shifted tile gw0s (L2-hot,
// same for all blocks) and applies the d0 scale at fragment-read time:
// the XOR-swizzle maps phase (ks,quad) to global k-chunk kc+(ks*4+quad)*8
// for every row, so ONE 16 B L1-hit load of d0b[ig][k-slice] per ks serves
// all 4 B-frags. Numerics bit-identical to kt_g0's (bf16)((f32)g*(f32)d).
// Proven: fp32 in/out, documented order, ws ~280 MB, trace math, XCD
// swizzle (FETCH 265->41->25 MB), occupancy 3 vs 4 blocks/CU equivalent.

typedef __bf16 bf16;
typedef __bf16 bf16x8 __attribute__((ext_vector_type(8)));
typedef float floatx4 __attribute__((ext_vector_type(4)));

#if defined(__has_builtin)
#if __has_builtin(__builtin_amdgcn_global_load_lds)
#define HAVE_GLL 1
#endif
#endif

typedef __attribute__((address_space(3))) char lds_char_t;
typedef __attribute__((address_space(1))) const char gbl_char_t;

__device__ inline void async_load16(const void* gp, void* lp) {
#ifdef HAVE_GLL
  __builtin_amdgcn_global_load_lds((gbl_char_t*)gp, (lds_char_t*)lp, 16, 0, 0);
#else
  *(bf16x8*)lp = *(const bf16x8*)gp;
#endif
}

// Stage a 128x64 bf16 tile into LDS with XOR-by-row chunk swizzle.
__device__ inline void stage_async(const bf16* src, long row0, int ld, int kc,
                                   bf16* dst, int wid, int sr8, int cph) {
#pragma unroll
  for (int t = 0; t < 4; ++t) {
    const int r = (wid * 4 + t) * 8 + sr8;
    const int csrc = (cph - r) & 7;
    async_load16(src + (row0 + r) * (size_t)ld + kc + csrc * 8,
                 dst + r * 64 + cph * 8);
  }
}

__device__ inline void mfma_block(const bf16* As, const bf16* Bs,
                                  floatx4 (&acc)[4][4], int wm, int wn,
                                  int l16, int quad) {
#pragma unroll
  for (int ks = 0; ks < 2; ++ks) {
    bf16x8 af[4], bfv[4];
#pragma unroll
    for (int mt = 0; mt < 4; ++mt) {
      const int r = wm * 64 + mt * 16 + l16;
      const int c = (ks * 4 + quad + r) & 7;
      af[mt] = *(const bf16x8*)(As + r * 64 + c * 8);
    }
#pragma unroll
    for (int nt = 0; nt < 4; ++nt) {
      const int r = wn * 64 + nt * 16 + l16;
      const int c = (ks * 4 + quad + r) & 7;
      bfv[nt] = *(const bf16x8*)(Bs + r * 64 + c * 8);
    }
#pragma unroll
    for (int mt = 0; mt < 4; ++mt)
#pragma unroll
      for (int nt = 0; nt < 4; ++nt)
        acc[mt][nt] = __builtin_amdgcn_mfma_f32_16x16x32_bf16(af[mt], bfv[nt], acc[mt][nt], 0, 0, 0);
  }
}

// ---------------- trace GEMMs ----------------
struct TArgs {
  const bf16* A;        // [1024][1024] (gw1t / gw2t, zero-padded)
  const bf16* B;        // B1: gw0s [128][1024] shared; B2: Upr [ch*128][1024]
  const bf16* d0b;      // B1: [1024][1024] (frag-read compose)
  const bf16* d1b;      // B1: [1024][960]
  bf16* Upr;            // B1 out: [ch*128][1024]
  const bf16* d2b;      // B2: [1024][896]
  const float* gdw;     // B2: [896][128] fp32
  float* tr;            // [1024]
  int i0; int K; int ch;
};

// MODE 0 = B1: U' rows = d1 * (gw1^T @ (d0 ⊙ gw0s)); MODE 1 = B2: trace reduce.
template <int MODE>
__global__ __launch_bounds__(256, 4) void kt_tile(TArgs p) {
  const int idx = blockIdx.x;
  const int mt8 = (idx >> 3) & 7;
  const int nb  = ((idx >> 6) << 3) + (idx & 7);
  if (nb >= p.ch) return;
  if (MODE == 1 && mt8 == 7) return;        // B2 has 7 m-tiles (M=896)

  __shared__ __align__(16) char lds[34816];
  bf16* As = (bf16*)lds;
  bf16* Bs = As + 8192;
  bf16* bounce = (bf16*)lds;
  __shared__ float red4[4];

  const int tid  = threadIdx.x;
  const int wid  = tid >> 6, lane = tid & 63;
  const int wm   = wid & 1, wn = wid >> 1;
  const int quad = lane >> 4, l16 = lane & 15;
  const int sr8  = lane >> 3, cph = lane & 7;
  const int m0   = mt8 * 128;
  const int ig   = p.i0 + nb;
  const int n0   = nb * 128;

  floatx4 acc[4][4];
#pragma unroll
  for (int a = 0; a < 4; ++a)
#pragma unroll
    for (int b = 0; b < 4; ++b)
#pragma unroll
      for (int r = 0; r < 4; ++r) acc[a][b][r] = 0.0f;

  for (int kc = 0; kc < p.K; kc += 64) {
    stage_async(p.A, m0, 1024, kc, As, wid, sr8, cph);
    stage_async(p.B, (MODE == 0) ? 0 : n0, 1024, kc, Bs, wid, sr8, cph);
    __syncthreads();
#pragma unroll
    for (int ks = 0; ks < 2; ++ks) {
      bf16x8 af[4], bfv[4];
      bf16x8 dv;
      if (MODE == 0)   // global k-chunk for phase (ks,quad) is row-invariant
        dv = *(const bf16x8*)(p.d0b + (size_t)ig * 1024 + kc + (ks * 4 + quad) * 8);
#pragma unroll
      for (int mt = 0; mt < 4; ++mt) {
        const int r = wm * 64 + mt * 16 + l16;
        const int c = (ks * 4 + quad + r) & 7;
        af[mt] = *(const bf16x8*)(As + r * 64 + c * 8);
      }
#pragma unroll
      for (int nt = 0; nt < 4; ++nt) {
        const int r = wn * 64 + nt * 16 + l16;
        const int c = (ks * 4 + quad + r) & 7;
        bfv[nt] = *(const bf16x8*)(Bs + r * 64 + c * 8);
        if (MODE == 0) {
#pragma unroll
          for (int e = 0; e < 8; ++e)
            bfv[nt][e] = (bf16)((float)bfv[nt][e] * (float)dv[e]);
        }
      }
#pragma unroll
      for (int mt = 0; mt < 4; ++mt)
#pragma unroll
        for (int nt = 0; nt < 4; ++nt)
          acc[mt][nt] = __builtin_amdgcn_mfma_f32_16x16x32_bf16(af[mt], bfv[nt], acc[mt][nt], 0, 0, 0);
    }
    __syncthreads();
  }

  if (MODE == 0) {
#pragma unroll
    for (int nt = 0; nt < 4; ++nt) {
      const int nl = wn * 64 + nt * 16 + l16;
#pragma unroll
      for (int mt = 0; mt < 4; ++mt)
#pragma unroll
        for (int r = 0; r < 4; ++r) {
          const int ml = wm * 64 + mt * 16 + quad * 4 + r;
          const int mg = m0 + ml;
          const float d1v = (mg < 960) ? (float)p.d1b[(size_t)ig * 960 + mg] : 0.0f;
          bounce[nl * 136 + ml] = (bf16)(acc[mt][nt][r] * d1v);
        }
    }
    __syncthreads();
    const int r2 = tid >> 1, half16 = tid & 1;
#pragma unroll
    for (int c = 0; c < 8; ++c) {
      const int ch16 = half16 * 8 + c;
      bf16x8 v = *(const bf16x8*)(bounce + r2 * 136 + ch16 * 8);
      *(bf16x8*)(p.Upr + (size_t)(n0 + r2) * 1024 + m0 + ch16 * 8) = v;
    }
  } else {
    float s = 0.0f;
#pragma unroll
    for (int nt = 0; nt < 4; ++nt) {
      const int d = wn * 64 + nt * 16 + l16;
      if (d < 127) {
#pragma unroll
        for (int mt = 0; mt < 4; ++mt)
#pragma unroll
          for (int r = 0; r < 4; ++r) {
            const int mg = m0 + wm * 64 + mt * 16 + quad * 4 + r;  // < 896
            const float w = (float)p.d2b[(size_t)ig * 896 + mg] * p.gdw[mg * 128 + d];
            s += acc[mt][nt][r] * w;
          }
      }
    }
#pragma unroll
    for (int off = 1; off < 64; off <<= 1) s += __shfl_xor(s, off, 64);
    if (lane == 0) red4[wid] = s;
    __syncthreads();
    if (tid == 0) atomicAdd(p.tr + ig, red4[0] + red4[1] + red4[2] + red4[3]);
  }
}

// ---------------- forward GEMMs ----------------
struct FArgs {
  const bf16* A; int lda;
  const bf16* Bt; int ldb;
  const float* bias;
  bf16* C; int ldc;
  bf16* D; int ldd;
  float* outF; int ldo;
  int K; int realN;
};

template <int ACT>
__global__ __launch_bounds__(256) void kt_fwd(FArgs p) {
  __shared__ __align__(16) bf16 As[8192];
  __shared__ __align__(16) bf16 Bs[8192];
  const int tid  = threadIdx.x;
  const int wid  = tid >> 6, lane = tid & 63;
  const int wm   = wid & 1, wn = wid >> 1;
  const int quad = lane >> 4, l16 = lane & 15;
  const int sr8  = lane >> 3, cph = lane & 7;
  const int m0   = blockIdx.x * 128;
  const int bn0  = blockIdx.y * 128;

  floatx4 acc[4][4];
#pragma unroll
  for (int a = 0; a < 4; ++a)
#pragma unroll
    for (int b = 0; b < 4; ++b)
#pragma unroll
      for (int r = 0; r < 4; ++r) acc[a][b][r] = 0.0f;

  for (int kc = 0; kc < p.K; kc += 64) {
    stage_async(p.A, m0, p.lda, kc, As, wid, sr8, cph);
    stage_async(p.Bt, bn0, p.ldb, kc, Bs, wid, sr8, cph);
    __syncthreads();
    mfma_block(As, Bs, acc, wm, wn, l16, quad);
    __syncthreads();
  }

#pragma unroll
  for (int nt = 0; nt < 4; ++nt) {
    const int ng = bn0 + wn * 64 + nt * 16 + l16;
    const float bv = (ng < p.realN) ? p.bias[ng] : 0.0f;
#pragma unroll
    for (int mt = 0; mt < 4; ++mt)
#pragma unroll
      for (int r = 0; r < 4; ++r) {
        const int i = m0 + wm * 64 + mt * 16 + quad * 4 + r;
        const float v = acc[mt][nt][r] + bv;
        if (ACT) {
          const float t = tanhf(v);
          p.C[(size_t)i * p.ldc + ng] = (ng < p.realN) ? (bf16)t : (bf16)0.0f;
          if (p.D && ng < p.realN)
            p.D[(size_t)i * p.ldd + ng] = (bf16)(1.0f - t * t);
        } else if (ng < p.realN) {
          p.outF[(size_t)i * p.ldo + ng] = v;
        }
      }
  }
}

// ---------------- fused prep with LDS-tiled transposes ----------------
struct PArgs {
  const float *gw0, *gw1, *gw2, *gdw, *bw0, *bw1, *pt, *x;
  bf16 *gw0s, *gw0t, *gw1t, *gw2t, *gdwt, *bw0t, *bw1t, *Xg, *Xb;
};

__device__ inline void tpose_tile(bf16* dst, const float* src, int R, int C,
                                  int ldd, int tile, int tilesX, float* tl,
                                  int tid) {
  const int r0 = (tile % tilesX) * 64;
  const int c0 = (tile / tilesX) * 64;
  const int tx = tid & 63, ty0 = tid >> 6;
#pragma unroll
  for (int i = 0; i < 16; ++i) {
    const int ty = ty0 + i * 4;
    const int r = r0 + ty, c = c0 + tx;
    tl[ty * 65 + tx] = (r < R && c < C) ? src[(size_t)r * C + c] : 0.0f;
  }
  __syncthreads();
#pragma unroll
  for (int i = 0; i < 16; ++i) {
    const int ty = ty0 + i * 4;
    dst[(size_t)(c0 + ty) * ldd + r0 + tx] = (bf16)tl[tx * 65 + ty];
  }
}

__global__ __launch_bounds__(256) void kt_prep(PArgs p) {
  __shared__ float tl[64 * 65];
  int b = blockIdx.x;
  const int t = threadIdx.x;
  if (b < 512) {  // gw0s[d][j] = (bf16)gw0[min(d+1,127)][j]
    const int idx = b * 256 + t;
    const int d = idx >> 10, j = idx & 1023;
    const int wsel = (d + 1 < 128) ? d + 1 : 127;
    p.gw0s[idx] = (bf16)p.gw0[wsel * 1024 + j];
    return;
  }
  b -= 512;
  if (b < 768) {  // build Xg/Xb
    const int idx = b * 256 + t;
    const int i = idx / 192, c = idx % 192;
    const float s = p.pt[0];
    float vb;
    if (c == 0) vb = s;
    else if (c <= 128) vb = p.x[i * 128 + c - 1];
    else vb = 0.0f;
    p.Xb[i * 192 + c] = (bf16)vb;
    if (c < 128) p.Xg[i * 128 + c] = (bf16)((c == 0) ? s : p.x[i * 128 + c - 1]);
    return;
  }
  b -= 768;
  if (b < 32)  { tpose_tile(p.gw0t, p.gw0, 128, 1024, 128, b, 2, tl, t);  return; }
  b -= 32;
  if (b < 256) { tpose_tile(p.gw1t, p.gw1, 1024, 960, 1024, b, 16, tl, t); return; }
  b -= 256;
  if (b < 256) { tpose_tile(p.gw2t, p.gw2, 960, 896, 1024, b, 16, tl, t); return; }
  b -= 256;
  if (b < 32)  { tpose_tile(p.gdwt, p.gdw, 896, 128, 1024, b, 16, tl, t); return; }
  b -= 32;
  if (b < 24)  { tpose_tile(p.bw0t, p.bw0, 129, 512, 192, b, 3, tl, t);  return; }
  b -= 24;
  if (b < 64)  { tpose_tile(p.bw1t, p.bw1, 512, 448, 512, b, 8, tl, t);  return; }
}

// ---------------- small helpers ----------------
__global__ __launch_bounds__(256) void kt_gdot(const bf16* e1b, const float* bdw,
                                               const float* bdb, float* gf, float* gout) {
  const int i = blockIdx.x * 4 + (threadIdx.x >> 6);
  const int lane = threadIdx.x & 63;
  float s = 0.0f;
  for (int k = lane; k < 448; k += 64) s += (float)e1b[(size_t)i * 512 + k] * bdw[k];
#pragma unroll
  for (int off = 32; off > 0; off >>= 1) s += __shfl_down(s, off, 64);
  if (lane == 0) {
    const float v = s + bdb[0];
    gf[i] = v;
    gout[i] = v;
  }
}

__global__ __launch_bounds__(256) void kt_fin(const float* gf, const float* tr,
                                              const float* pp, float* dp) {
  const int i = blockIdx.x * 256 + threadIdx.x;
  if (i < 1024) dp[i] = gf[i] - pp[i] * tr[i];
}

extern "C" void kernel_launch(void* const* d_in, const int* in_sizes, int n_in,
                              void* d_out, int out_size, void* d_ws, size_t ws_size,
                              hipStream_t stream) {
  const float* pt  = (const float*)d_in[0];
  const float* x   = (const float*)d_in[1];
  const float* pp  = (const float*)d_in[3];
  const float* gw0 = (const float*)d_in[4];
  const float* gb0 = (const float*)d_in[5];
  const float* gw1 = (const float*)d_in[6];
  const float* gb1 = (const float*)d_in[7];
  const float* gw2 = (const float*)d_in[8];
  const float* gb2 = (const float*)d_in[9];
  const float* gdw = (const float*)d_in[10];
  const float* gdb = (const float*)d_in[11];
  const float* bw0 = (const float*)d_in[12];
  const float* bb0 = (const float*)d_in[13];
  const float* bw1 = (const float*)d_in[14];
  const float* bb1 = (const float*)d_in[15];
  const float* bdw = (const float*)d_in[16];
  const float* bdb = (const float*)d_in[17];
  float* out = (float*)d_out;

  char* w = (char*)d_ws;
  size_t used = 0;
  auto alloc = [&](size_t nbytes) -> void* {
    void* r = w + used;
    used += (nbytes + 255) & ~(size_t)255;
    return r;
  };
  bf16* gw0s = (bf16*)alloc((size_t)128 * 1024 * 2);   // shifted gw0 (shared B1 B-tile)
  bf16* gw0t = (bf16*)alloc((size_t)1024 * 128 * 2);
  bf16* gw1t = (bf16*)alloc((size_t)1024 * 1024 * 2);
  bf16* gw2t = (bf16*)alloc((size_t)1024 * 1024 * 2);
  bf16* gdwt = (bf16*)alloc((size_t)128 * 1024 * 2);
  bf16* bw0t = (bf16*)alloc((size_t)512 * 192 * 2);
  bf16* bw1t = (bf16*)alloc((size_t)512 * 512 * 2);
  bf16* Xg   = (bf16*)alloc((size_t)1024 * 128 * 2);
  bf16* Xb   = (bf16*)alloc((size_t)1024 * 192 * 2);
  bf16* h0b  = (bf16*)alloc((size_t)1024 * 1024 * 2);
  bf16* h1b  = (bf16*)alloc((size_t)1024 * 1024 * 2);
  bf16* h2b  = (bf16*)alloc((size_t)1024 * 1024 * 2);
  bf16* e0b  = (bf16*)alloc((size_t)1024 * 512 * 2);
  bf16* e1b  = (bf16*)alloc((size_t)1024 * 512 * 2);
  bf16* d0b  = (bf16*)alloc((size_t)1024 * 1024 * 2);
  bf16* d1b  = (bf16*)alloc((size_t)1024 * 960 * 2);
  bf16* d2b  = (bf16*)alloc((size_t)1024 * 896 * 2);
  float* gf  = (float*)alloc(1024 * 4);
  float* tr  = (float*)alloc(1024 * 4);

  const size_t perSample = (size_t)128 * 1024 * 2;     // 256 KB (Upr only now)
  size_t avail = (ws_size > used) ? ws_size - used : 0;
  int CH = (int)(avail / perSample);
  if (CH > 256) CH = 256;   // 4 chunks; Upr = 64 MB, deeply L3-resident
  if (CH < 1) CH = 1;
  bf16* Upr = (bf16*)(w + used);

  hipMemsetAsync(tr, 0, 1024 * 4, stream);

  {
    PArgs a{gw0, gw1, gw2, gdw, bw0, bw1, pt, x,
            gw0s, gw0t, gw1t, gw2t, gdwt, bw0t, bw1t, Xg, Xb};
    kt_prep<<<dim3(1944), 256, 0, stream>>>(a);
  }

  {  // L0
    FArgs a{}; a.A = Xg; a.lda = 128; a.Bt = gw0t; a.ldb = 128; a.bias = gb0;
    a.C = h0b; a.ldc = 1024; a.D = d0b; a.ldd = 1024; a.K = 128; a.realN = 1024;
    kt_fwd<1><<<dim3(8, 8), 256, 0, stream>>>(a);
  }
  {  // L1
    FArgs a{}; a.A = h0b; a.lda = 1024; a.Bt = gw1t; a.ldb = 1024; a.bias = gb1;
    a.C = h1b; a.ldc = 1024; a.D = d1b; a.ldd = 960; a.K = 1024; a.realN = 960;
    kt_fwd<1><<<dim3(8, 8), 256, 0, stream>>>(a);
  }
  {  // L2
    FArgs a{}; a.A = h1b; a.lda = 1024; a.Bt = gw2t; a.ldb = 1024; a.bias = gb2;
    a.C = h2b; a.ldc = 1024; a.D = d2b; a.ldd = 896; a.K = 1024; a.realN = 896;
    kt_fwd<1><<<dim3(8, 7), 256, 0, stream>>>(a);
  }
  {  // dx_dt
    FArgs a{}; a.A = h2b; a.lda = 1024; a.Bt = gdwt; a.ldb = 1024; a.bias = gdb;
    a.outF = out; a.ldo = 128; a.K = 896; a.realN = 128;
    kt_fwd<0><<<dim3(8, 1), 256, 0, stream>>>(a);
  }
  {  // e0
    FArgs a{}; a.A = Xb; a.lda = 192; a.Bt = bw0t; a.ldb = 192; a.bias = bb0;
    a.C = e0b; a.ldc = 512; a.K = 192; a.realN = 512;
    kt_fwd<1><<<dim3(8, 4), 256, 0, stream>>>(a);
  }
  {  // e1
    FArgs a{}; a.A = e0b; a.lda = 512; a.Bt = bw1t; a.ldb = 512; a.bias = bb1;
    a.C = e1b; a.ldc = 512; a.K = 512; a.realN = 448;
    kt_fwd<1><<<dim3(8, 4), 256, 0, stream>>>(a);
  }
  kt_gdot<<<dim3(256), 256, 0, stream>>>(e1b, bdw, bdb, gf, out + 131072);

  for (int i0 = 0; i0 < 1024; i0 += CH) {
    const int ch = (1024 - i0 < CH) ? (1024 - i0) : CH;
    const int ch8 = (ch + 7) & ~7;
    {  // B1: U' = D1 * (gw1^T @ (d0 ⊙ gw0s)), frag-read compose
      TArgs a{}; a.A = gw1t; a.B = gw0s; a.d0b = d0b; a.d1b = d1b; a.Upr = Upr;
      a.i0 = i0; a.K = 1024; a.ch = ch;
      kt_tile<0><<<dim3(8 * ch8), 256, 0, stream>>>(a);
    }
    {  // B2: trace reduce of gw2^T @ U', M=896 (mt==7 exits), K=960
      TArgs a{}; a.A = gw2t; a.B = Upr; a.d2b = d2b; a.gdw = gdw; a.tr = tr;
      a.i0 = i0; a.K = 960; a.ch = ch;
      kt_tile<1><<<dim3(8 * ch8), 256, 0, stream>>>(a);
    }
  }

  kt_fin<<<dim3(4), 256, 0, stream>>>(gf, tr, pp, out + 132096);
}

// Round 15
// 896.330 us; speedup vs baseline: 1.1093x; 1.1093x over previous
//
#include <hip/hip_runtime.h>

// R15: revert to R13 (proven 847 µs) after R14's frag-read compose regression
// (VALU on the ds_read->MFMA critical path: MfmaUtil 31.5->19.8, B1 +57%).
// Materialized G0 restored; lesson: elementwise composition belongs in a
// bandwidth-bound producer (kt_g0), never in the MFMA consumer's inner loop.
// One safe trim vs R13: B1's mt8==7 tile stores only columns <960 of U'
// (B2 runs K=960 and never reads the pad columns).
// Proven: fp32 in/out, documented order, ws ~283 MB, trace math, XCD
// swizzle, occupancy invariance, chunk-size invariance.

typedef __bf16 bf16;
typedef __bf16 bf16x8 __attribute__((ext_vector_type(8)));
typedef float floatx4 __attribute__((ext_vector_type(4)));

#if defined(__has_builtin)
#if __has_builtin(__builtin_amdgcn_global_load_lds)
#define HAVE_GLL 1
#endif
#endif

typedef __attribute__((address_space(3))) char lds_char_t;
typedef __attribute__((address_space(1))) const char gbl_char_t;

__device__ inline void async_load16(const void* gp, void* lp) {
#ifdef HAVE_GLL
  __builtin_amdgcn_global_load_lds((gbl_char_t*)gp, (lds_char_t*)lp, 16, 0, 0);
#else
  *(bf16x8*)lp = *(const bf16x8*)gp;
#endif
}

// Stage a 128x64 bf16 tile into LDS with XOR-by-row chunk swizzle.
__device__ inline void stage_async(const bf16* src, long row0, int ld, int kc,
                                   bf16* dst, int wid, int sr8, int cph) {
#pragma unroll
  for (int t = 0; t < 4; ++t) {
    const int r = (wid * 4 + t) * 8 + sr8;
    const int csrc = (cph - r) & 7;
    async_load16(src + (row0 + r) * (size_t)ld + kc + csrc * 8,
                 dst + r * 64 + cph * 8);
  }
}

__device__ inline void mfma_block(const bf16* As, const bf16* Bs,
                                  floatx4 (&acc)[4][4], int wm, int wn,
                                  int l16, int quad) {
#pragma unroll
  for (int ks = 0; ks < 2; ++ks) {
    bf16x8 af[4], bfv[4];
#pragma unroll
    for (int mt = 0; mt < 4; ++mt) {
      const int r = wm * 64 + mt * 16 + l16;
      const int c = (ks * 4 + quad + r) & 7;
      af[mt] = *(const bf16x8*)(As + r * 64 + c * 8);
    }
#pragma unroll
    for (int nt = 0; nt < 4; ++nt) {
      const int r = wn * 64 + nt * 16 + l16;
      const int c = (ks * 4 + quad + r) & 7;
      bfv[nt] = *(const bf16x8*)(Bs + r * 64 + c * 8);
    }
#pragma unroll
    for (int mt = 0; mt < 4; ++mt)
#pragma unroll
      for (int nt = 0; nt < 4; ++nt)
        acc[mt][nt] = __builtin_amdgcn_mfma_f32_16x16x32_bf16(af[mt], bfv[nt], acc[mt][nt], 0, 0, 0);
  }
}

// ---------------- trace GEMMs (R13 form) ----------------
struct TArgs {
  const bf16* A;        // [1024][1024] (gw1t / gw2t, zero-padded)
  const bf16* B;        // [ch*128][1024] (G0 for B1, Upr for B2)
  const bf16* d1b;      // B1: [1024][960]
  bf16* Upr;            // B1 out: [ch*128][1024]
  const bf16* d2b;      // B2: [1024][896]
  const float* gdw;     // B2: [896][128] fp32
  float* tr;            // [1024]
  int i0; int K; int ch;
};

// MODE 0 = B1: U' rows = d1 * (gw1^T @ G0-rows); MODE 1 = B2: trace reduce.
template <int MODE>
__global__ __launch_bounds__(256, 4) void kt_tile(TArgs p) {
  const int idx = blockIdx.x;
  const int mt8 = (idx >> 3) & 7;
  const int nb  = ((idx >> 6) << 3) + (idx & 7);
  if (nb >= p.ch) return;
  if (MODE == 1 && mt8 == 7) return;        // B2 has 7 m-tiles (M=896)

  __shared__ __align__(16) char lds[34816];
  bf16* As = (bf16*)lds;
  bf16* Bs = As + 8192;
  bf16* bounce = (bf16*)lds;
  __shared__ float red4[4];

  const int tid  = threadIdx.x;
  const int wid  = tid >> 6, lane = tid & 63;
  const int wm   = wid & 1, wn = wid >> 1;
  const int quad = lane >> 4, l16 = lane & 15;
  const int sr8  = lane >> 3, cph = lane & 7;
  const int m0   = mt8 * 128;
  const int ig   = p.i0 + nb;
  const int n0   = nb * 128;

  floatx4 acc[4][4];
#pragma unroll
  for (int a = 0; a < 4; ++a)
#pragma unroll
    for (int b = 0; b < 4; ++b)
#pragma unroll
      for (int r = 0; r < 4; ++r) acc[a][b][r] = 0.0f;

  for (int kc = 0; kc < p.K; kc += 64) {
    stage_async(p.A, m0, 1024, kc, As, wid, sr8, cph);
    stage_async(p.B, n0, 1024, kc, Bs, wid, sr8, cph);
    __syncthreads();
    mfma_block(As, Bs, acc, wm, wn, l16, quad);
    __syncthreads();
  }

  if (MODE == 0) {
#pragma unroll
    for (int nt = 0; nt < 4; ++nt) {
      const int nl = wn * 64 + nt * 16 + l16;
#pragma unroll
      for (int mt = 0; mt < 4; ++mt)
#pragma unroll
        for (int r = 0; r < 4; ++r) {
          const int ml = wm * 64 + mt * 16 + quad * 4 + r;
          const int mg = m0 + ml;
          const float d1v = (mg < 960) ? (float)p.d1b[(size_t)ig * 960 + mg] : 0.0f;
          bounce[nl * 136 + ml] = (bf16)(acc[mt][nt][r] * d1v);
        }
    }
    __syncthreads();
    const int r2 = tid >> 1, half16 = tid & 1;
    // mt8==7 covers U' columns 896..1023; only 896..959 are consumed
    // (B2 runs K=960) -> store only ch16 < 8 there.
    const int chLim = (mt8 == 7) ? 8 : 16;
#pragma unroll
    for (int c = 0; c < 8; ++c) {
      const int ch16 = half16 * 8 + c;
      if (ch16 < chLim) {
        bf16x8 v = *(const bf16x8*)(bounce + r2 * 136 + ch16 * 8);
        *(bf16x8*)(p.Upr + (size_t)(n0 + r2) * 1024 + m0 + ch16 * 8) = v;
      }
    }
  } else {
    float s = 0.0f;
#pragma unroll
    for (int nt = 0; nt < 4; ++nt) {
      const int d = wn * 64 + nt * 16 + l16;
      if (d < 127) {
#pragma unroll
        for (int mt = 0; mt < 4; ++mt)
#pragma unroll
          for (int r = 0; r < 4; ++r) {
            const int mg = m0 + wm * 64 + mt * 16 + quad * 4 + r;  // < 896
            const float w = (float)p.d2b[(size_t)ig * 896 + mg] * p.gdw[mg * 128 + d];
            s += acc[mt][nt][r] * w;
          }
      }
    }
#pragma unroll
    for (int off = 1; off < 64; off <<= 1) s += __shfl_xor(s, off, 64);
    if (lane == 0) red4[wid] = s;
    __syncthreads();
    if (tid == 0) atomicAdd(p.tr + ig, red4[0] + red4[1] + red4[2] + red4[3]);
  }
}

// ---------------- forward GEMMs ----------------
struct FArgs {
  const bf16* A; int lda;
  const bf16* Bt; int ldb;
  const float* bias;
  bf16* C; int ldc;
  bf16* D; int ldd;
  float* outF; int ldo;
  int K; int realN;
};

template <int ACT>
__global__ __launch_bounds__(256) void kt_fwd(FArgs p) {
  __shared__ __align__(16) bf16 As[8192];
  __shared__ __align__(16) bf16 Bs[8192];
  const int tid  = threadIdx.x;
  const int wid  = tid >> 6, lane = tid & 63;
  const int wm   = wid & 1, wn = wid >> 1;
  const int quad = lane >> 4, l16 = lane & 15;
  const int sr8  = lane >> 3, cph = lane & 7;
  const int m0   = blockIdx.x * 128;
  const int bn0  = blockIdx.y * 128;

  floatx4 acc[4][4];
#pragma unroll
  for (int a = 0; a < 4; ++a)
#pragma unroll
    for (int b = 0; b < 4; ++b)
#pragma unroll
      for (int r = 0; r < 4; ++r) acc[a][b][r] = 0.0f;

  for (int kc = 0; kc < p.K; kc += 64) {
    stage_async(p.A, m0, p.lda, kc, As, wid, sr8, cph);
    stage_async(p.Bt, bn0, p.ldb, kc, Bs, wid, sr8, cph);
    __syncthreads();
    mfma_block(As, Bs, acc, wm, wn, l16, quad);
    __syncthreads();
  }

#pragma unroll
  for (int nt = 0; nt < 4; ++nt) {
    const int ng = bn0 + wn * 64 + nt * 16 + l16;
    const float bv = (ng < p.realN) ? p.bias[ng] : 0.0f;
#pragma unroll
    for (int mt = 0; mt < 4; ++mt)
#pragma unroll
      for (int r = 0; r < 4; ++r) {
        const int i = m0 + wm * 64 + mt * 16 + quad * 4 + r;
        const float v = acc[mt][nt][r] + bv;
        if (ACT) {
          const float t = tanhf(v);
          p.C[(size_t)i * p.ldc + ng] = (ng < p.realN) ? (bf16)t : (bf16)0.0f;
          if (p.D && ng < p.realN)
            p.D[(size_t)i * p.ldd + ng] = (bf16)(1.0f - t * t);
        } else if (ng < p.realN) {
          p.outF[(size_t)i * p.ldo + ng] = v;
        }
      }
  }
}

// ---------------- fused prep with LDS-tiled transposes ----------------
struct PArgs {
  const float *gw0, *gw1, *gw2, *gdw, *bw0, *bw1, *pt, *x;
  bf16 *gw0b, *gw0t, *gw1t, *gw2t, *gdwt, *bw0t, *bw1t, *Xg, *Xb;
};

__device__ inline void tpose_tile(bf16* dst, const float* src, int R, int C,
                                  int ldd, int tile, int tilesX, float* tl,
                                  int tid) {
  const int r0 = (tile % tilesX) * 64;
  const int c0 = (tile / tilesX) * 64;
  const int tx = tid & 63, ty0 = tid >> 6;
#pragma unroll
  for (int i = 0; i < 16; ++i) {
    const int ty = ty0 + i * 4;
    const int r = r0 + ty, c = c0 + tx;
    tl[ty * 65 + tx] = (r < R && c < C) ? src[(size_t)r * C + c] : 0.0f;
  }
  __syncthreads();
#pragma unroll
  for (int i = 0; i < 16; ++i) {
    const int ty = ty0 + i * 4;
    dst[(size_t)(c0 + ty) * ldd + r0 + tx] = (bf16)tl[tx * 65 + ty];
  }
}

__global__ __launch_bounds__(256) void kt_prep(PArgs p) {
  __shared__ float tl[64 * 65];
  int b = blockIdx.x;
  const int t = threadIdx.x;
  if (b < 512) { p.gw0b[b * 256 + t] = (bf16)p.gw0[b * 256 + t]; return; }
  b -= 512;
  if (b < 768) {  // build Xg/Xb
    const int idx = b * 256 + t;
    const int i = idx / 192, c = idx % 192;
    const float s = p.pt[0];
    float vb;
    if (c == 0) vb = s;
    else if (c <= 128) vb = p.x[i * 128 + c - 1];
    else vb = 0.0f;
    p.Xb[i * 192 + c] = (bf16)vb;
    if (c < 128) p.Xg[i * 128 + c] = (bf16)((c == 0) ? s : p.x[i * 128 + c - 1]);
    return;
  }
  b -= 768;
  if (b < 32)  { tpose_tile(p.gw0t, p.gw0, 128, 1024, 128, b, 2, tl, t);  return; }
  b -= 32;
  if (b < 256) { tpose_tile(p.gw1t, p.gw1, 1024, 960, 1024, b, 16, tl, t); return; }
  b -= 256;
  if (b < 256) { tpose_tile(p.gw2t, p.gw2, 960, 896, 1024, b, 16, tl, t); return; }
  b -= 256;
  if (b < 32)  { tpose_tile(p.gdwt, p.gdw, 896, 128, 1024, b, 16, tl, t); return; }
  b -= 32;
  if (b < 24)  { tpose_tile(p.bw0t, p.bw0, 129, 512, 192, b, 3, tl, t);  return; }
  b -= 24;
  if (b < 64)  { tpose_tile(p.bw1t, p.bw1, 512, 448, 512, b, 8, tl, t);  return; }
}

// ---------------- small helpers ----------------
// G0 compose, XCD-aligned with B1's reader mapping.
__global__ __launch_bounds__(256) void kt_g0(bf16* G0, const bf16* gw0b,
                                             const bf16* d0b, int i0, int ch) {
  const int b = blockIdx.x;
  const int nb = ((b >> 9) << 3) + (b & 7);
  const int inner = (b >> 3) & 63;
  if (nb >= ch) return;
  const int e = inner * 256 + threadIdx.x;
  const int d = e >> 7;
  const int j = (e & 127) << 3;
  const int ig = i0 + nb;
  const int wsel = (d + 1 < 128) ? d + 1 : 127;   // d==127 pad (masked in B2)
  bf16x8 gv = *(const bf16x8*)(gw0b + wsel * 1024 + j);
  bf16x8 dv = *(const bf16x8*)(d0b + (size_t)ig * 1024 + j);
  bf16x8 v;
#pragma unroll
  for (int k = 0; k < 8; ++k) v[k] = (bf16)((float)gv[k] * (float)dv[k]);
  *(bf16x8*)(G0 + ((size_t)nb * 128 + d) * 1024 + j) = v;
}

__global__ __launch_bounds__(256) void kt_gdot(const bf16* e1b, const float* bdw,
                                               const float* bdb, float* gf, float* gout) {
  const int i = blockIdx.x * 4 + (threadIdx.x >> 6);
  const int lane = threadIdx.x & 63;
  float s = 0.0f;
  for (int k = lane; k < 448; k += 64) s += (float)e1b[(size_t)i * 512 + k] * bdw[k];
#pragma unroll
  for (int off = 32; off > 0; off >>= 1) s += __shfl_down(s, off, 64);
  if (lane == 0) {
    const float v = s + bdb[0];
    gf[i] = v;
    gout[i] = v;
  }
}

__global__ __launch_bounds__(256) void kt_fin(const float* gf, const float* tr,
                                              const float* pp, float* dp) {
  const int i = blockIdx.x * 256 + threadIdx.x;
  if (i < 1024) dp[i] = gf[i] - pp[i] * tr[i];
}

extern "C" void kernel_launch(void* const* d_in, const int* in_sizes, int n_in,
                              void* d_out, int out_size, void* d_ws, size_t ws_size,
                              hipStream_t stream) {
  const float* pt  = (const float*)d_in[0];
  const float* x   = (const float*)d_in[1];
  const float* pp  = (const float*)d_in[3];
  const float* gw0 = (const float*)d_in[4];
  const float* gb0 = (const float*)d_in[5];
  const float* gw1 = (const float*)d_in[6];
  const float* gb1 = (const float*)d_in[7];
  const float* gw2 = (const float*)d_in[8];
  const float* gb2 = (const float*)d_in[9];
  const float* gdw = (const float*)d_in[10];
  const float* gdb = (const float*)d_in[11];
  const float* bw0 = (const float*)d_in[12];
  const float* bb0 = (const float*)d_in[13];
  const float* bw1 = (const float*)d_in[14];
  const float* bb1 = (const float*)d_in[15];
  const float* bdw = (const float*)d_in[16];
  const float* bdb = (const float*)d_in[17];
  float* out = (float*)d_out;

  char* w = (char*)d_ws;
  size_t used = 0;
  auto alloc = [&](size_t nbytes) -> void* {
    void* r = w + used;
    used += (nbytes + 255) & ~(size_t)255;
    return r;
  };
  bf16* gw0b = (bf16*)alloc((size_t)128 * 1024 * 2);
  bf16* gw0t = (bf16*)alloc((size_t)1024 * 128 * 2);
  bf16* gw1t = (bf16*)alloc((size_t)1024 * 1024 * 2);
  bf16* gw2t = (bf16*)alloc((size_t)1024 * 1024 * 2);
  bf16* gdwt = (bf16*)alloc((size_t)128 * 1024 * 2);
  bf16* bw0t = (bf16*)alloc((size_t)512 * 192 * 2);
  bf16* bw1t = (bf16*)alloc((size_t)512 * 512 * 2);
  bf16* Xg   = (bf16*)alloc((size_t)1024 * 128 * 2);
  bf16* Xb   = (bf16*)alloc((size_t)1024 * 192 * 2);
  bf16* h0b  = (bf16*)alloc((size_t)1024 * 1024 * 2);
  bf16* h1b  = (bf16*)alloc((size_t)1024 * 1024 * 2);
  bf16* h2b  = (bf16*)alloc((size_t)1024 * 1024 * 2);
  bf16* e0b  = (bf16*)alloc((size_t)1024 * 512 * 2);
  bf16* e1b  = (bf16*)alloc((size_t)1024 * 512 * 2);
  bf16* d0b  = (bf16*)alloc((size_t)1024 * 1024 * 2);
  bf16* d1b  = (bf16*)alloc((size_t)1024 * 960 * 2);
  bf16* d2b  = (bf16*)alloc((size_t)1024 * 896 * 2);
  float* gf  = (float*)alloc(1024 * 4);
  float* tr  = (float*)alloc(1024 * 4);

  const size_t perSample = (size_t)128 * 1024 * 2;     // 256 KB
  size_t avail = (ws_size > used) ? ws_size - used : 0;
  int CH = (int)(avail / (2 * perSample));
  if (CH > 256) CH = 256;   // 4 chunks; G0+Upr = 128 MB stays L3-resident
  if (CH < 1) CH = 1;
  bf16* G0  = (bf16*)alloc((size_t)CH * perSample);
  bf16* Upr = (bf16*)(w + used);

  hipMemsetAsync(tr, 0, 1024 * 4, stream);

  {
    PArgs a{gw0, gw1, gw2, gdw, bw0, bw1, pt, x,
            gw0b, gw0t, gw1t, gw2t, gdwt, bw0t, bw1t, Xg, Xb};
    kt_prep<<<dim3(1944), 256, 0, stream>>>(a);
  }

  {  // L0
    FArgs a{}; a.A = Xg; a.lda = 128; a.Bt = gw0t; a.ldb = 128; a.bias = gb0;
    a.C = h0b; a.ldc = 1024; a.D = d0b; a.ldd = 1024; a.K = 128; a.realN = 1024;
    kt_fwd<1><<<dim3(8, 8), 256, 0, stream>>>(a);
  }
  {  // L1
    FArgs a{}; a.A = h0b; a.lda = 1024; a.Bt = gw1t; a.ldb = 1024; a.bias = gb1;
    a.C = h1b; a.ldc = 1024; a.D = d1b; a.ldd = 960; a.K = 1024; a.realN = 960;
    kt_fwd<1><<<dim3(8, 8), 256, 0, stream>>>(a);
  }
  {  // L2
    FArgs a{}; a.A = h1b; a.lda = 1024; a.Bt = gw2t; a.ldb = 1024; a.bias = gb2;
    a.C = h2b; a.ldc = 1024; a.D = d2b; a.ldd = 896; a.K = 1024; a.realN = 896;
    kt_fwd<1><<<dim3(8, 7), 256, 0, stream>>>(a);
  }
  {  // dx_dt
    FArgs a{}; a.A = h2b; a.lda = 1024; a.Bt = gdwt; a.ldb = 1024; a.bias = gdb;
    a.outF = out; a.ldo = 128; a.K = 896; a.realN = 128;
    kt_fwd<0><<<dim3(8, 1), 256, 0, stream>>>(a);
  }
  {  // e0
    FArgs a{}; a.A = Xb; a.lda = 192; a.Bt = bw0t; a.ldb = 192; a.bias = bb0;
    a.C = e0b; a.ldc = 512; a.K = 192; a.realN = 512;
    kt_fwd<1><<<dim3(8, 4), 256, 0, stream>>>(a);
  }
  {  // e1
    FArgs a{}; a.A = e0b; a.lda = 512; a.Bt = bw1t; a.ldb = 512; a.bias = bb1;
    a.C = e1b; a.ldc = 512; a.K = 512; a.realN = 448;
    kt_fwd<1><<<dim3(8, 4), 256, 0, stream>>>(a);
  }
  kt_gdot<<<dim3(256), 256, 0, stream>>>(e1b, bdw, bdb, gf, out + 131072);

  for (int i0 = 0; i0 < 1024; i0 += CH) {
    const int ch = (1024 - i0 < CH) ? (1024 - i0) : CH;
    const int ch8 = (ch + 7) & ~7;
    kt_g0<<<dim3(ch8 * 64), 256, 0, stream>>>(G0, gw0b, d0b, i0, ch);
    {  // B1: U' = D1 * (gw1^T @ G0), M pad 1024, K=1024
      TArgs a{}; a.A = gw1t; a.B = G0; a.d1b = d1b; a.Upr = Upr; a.i0 = i0;
      a.K = 1024; a.ch = ch;
      kt_tile<0><<<dim3(8 * ch8), 256, 0, stream>>>(a);
    }
    {  // B2: trace reduce of gw2^T @ U', M=896 (mt==7 exits), K=960
      TArgs a{}; a.A = gw2t; a.B = Upr; a.d2b = d2b; a.gdw = gdw; a.tr = tr;
      a.i0 = i0; a.K = 960; a.ch = ch;
      kt_tile<1><<<dim3(8 * ch8), 256, 0, stream>>>(a);
    }
  }

  kt_fin<<<dim3(4), 256, 0, stream>>>(gf, tr, pp, out + 132096);
}

// Round 16
// 793.142 us; speedup vs baseline: 1.2537x; 1.1301x over previous
//
#include <hip/hip_runtime.h>

// R16: dispatch-fusion round (GEMM kernels byte-identical to R13/R15).
// The trace GEMMs are at the m97-structure plateau (B1 ~737 TF, MfmaUtil
// ~31.5%); remaining waste is stream serialization of independent work:
//   F1 = L0 ∪ e0          (both read only inputs)
//   F2 = L1 ∪ e1
//   F3 = L2 ∪ g0(chunk0)  (g0 needs only d0b; streams while L2 computes)
//   F4 = dx ∪ gdot
//   loop: B1(ci) ; B2(ci) ∪ g0(ci+1)   (B2 never reads G0; B1 done with it)
// 21 -> 13 dispatches; all offsets ≡ 0 mod 8 keep XCD phase; numerics
// unchanged (absmax must stay 0.009765625).

typedef __bf16 bf16;
typedef __bf16 bf16x8 __attribute__((ext_vector_type(8)));
typedef float floatx4 __attribute__((ext_vector_type(4)));

#if defined(__has_builtin)
#if __has_builtin(__builtin_amdgcn_global_load_lds)
#define HAVE_GLL 1
#endif
#endif

typedef __attribute__((address_space(3))) char lds_char_t;
typedef __attribute__((address_space(1))) const char gbl_char_t;

__device__ inline void async_load16(const void* gp, void* lp) {
#ifdef HAVE_GLL
  __builtin_amdgcn_global_load_lds((gbl_char_t*)gp, (lds_char_t*)lp, 16, 0, 0);
#else
  *(bf16x8*)lp = *(const bf16x8*)gp;
#endif
}

__device__ inline void stage_async(const bf16* src, long row0, int ld, int kc,
                                   bf16* dst, int wid, int sr8, int cph) {
#pragma unroll
  for (int t = 0; t < 4; ++t) {
    const int r = (wid * 4 + t) * 8 + sr8;
    const int csrc = (cph - r) & 7;
    async_load16(src + (row0 + r) * (size_t)ld + kc + csrc * 8,
                 dst + r * 64 + cph * 8);
  }
}

__device__ inline void mfma_block(const bf16* As, const bf16* Bs,
                                  floatx4 (&acc)[4][4], int wm, int wn,
                                  int l16, int quad) {
#pragma unroll
  for (int ks = 0; ks < 2; ++ks) {
    bf16x8 af[4], bfv[4];
#pragma unroll
    for (int mt = 0; mt < 4; ++mt) {
      const int r = wm * 64 + mt * 16 + l16;
      const int c = (ks * 4 + quad + r) & 7;
      af[mt] = *(const bf16x8*)(As + r * 64 + c * 8);
    }
#pragma unroll
    for (int nt = 0; nt < 4; ++nt) {
      const int r = wn * 64 + nt * 16 + l16;
      const int c = (ks * 4 + quad + r) & 7;
      bfv[nt] = *(const bf16x8*)(Bs + r * 64 + c * 8);
    }
#pragma unroll
    for (int mt = 0; mt < 4; ++mt)
#pragma unroll
      for (int nt = 0; nt < 4; ++nt)
        acc[mt][nt] = __builtin_amdgcn_mfma_f32_16x16x32_bf16(af[mt], bfv[nt], acc[mt][nt], 0, 0, 0);
  }
}

// ---------------- G0 compose body (shared by fused dispatches) ----------------
__device__ inline void g0_body(bf16* G0, const bf16* gw0b, const bf16* d0b,
                               int i0, int ch, int b, int tid) {
  const int nb = ((b >> 9) << 3) + (b & 7);
  const int inner = (b >> 3) & 63;
  if (nb >= ch) return;
  const int e = inner * 256 + tid;
  const int d = e >> 7;
  const int j = (e & 127) << 3;
  const int ig = i0 + nb;
  const int wsel = (d + 1 < 128) ? d + 1 : 127;   // d==127 pad (masked in B2)
  bf16x8 gv = *(const bf16x8*)(gw0b + wsel * 1024 + j);
  bf16x8 dv = *(const bf16x8*)(d0b + (size_t)ig * 1024 + j);
  bf16x8 v;
#pragma unroll
  for (int k = 0; k < 8; ++k) v[k] = (bf16)((float)gv[k] * (float)dv[k]);
  *(bf16x8*)(G0 + ((size_t)nb * 128 + d) * 1024 + j) = v;
}

// ---------------- trace GEMMs ----------------
struct TArgs {
  const bf16* A;
  const bf16* B;
  const bf16* d1b;
  bf16* Upr;
  const bf16* d2b;
  const float* gdw;
  float* tr;
  int i0; int K; int ch;
};

// B1: U' rows = d1 * (gw1^T @ G0-rows)
__global__ __launch_bounds__(256, 4) void kt_b1(TArgs p) {
  const int idx = blockIdx.x;
  const int mt8 = (idx >> 3) & 7;
  const int nb  = ((idx >> 6) << 3) + (idx & 7);
  if (nb >= p.ch) return;

  __shared__ __align__(16) char lds[34816];
  bf16* As = (bf16*)lds;
  bf16* Bs = As + 8192;
  bf16* bounce = (bf16*)lds;

  const int tid  = threadIdx.x;
  const int wid  = tid >> 6, lane = tid & 63;
  const int wm   = wid & 1, wn = wid >> 1;
  const int quad = lane >> 4, l16 = lane & 15;
  const int sr8  = lane >> 3, cph = lane & 7;
  const int m0   = mt8 * 128;
  const int ig   = p.i0 + nb;
  const int n0   = nb * 128;

  floatx4 acc[4][4];
#pragma unroll
  for (int a = 0; a < 4; ++a)
#pragma unroll
    for (int b = 0; b < 4; ++b)
#pragma unroll
      for (int r = 0; r < 4; ++r) acc[a][b][r] = 0.0f;

  for (int kc = 0; kc < p.K; kc += 64) {
    stage_async(p.A, m0, 1024, kc, As, wid, sr8, cph);
    stage_async(p.B, n0, 1024, kc, Bs, wid, sr8, cph);
    __syncthreads();
    mfma_block(As, Bs, acc, wm, wn, l16, quad);
    __syncthreads();
  }

#pragma unroll
  for (int nt = 0; nt < 4; ++nt) {
    const int nl = wn * 64 + nt * 16 + l16;
#pragma unroll
    for (int mt = 0; mt < 4; ++mt)
#pragma unroll
      for (int r = 0; r < 4; ++r) {
        const int ml = wm * 64 + mt * 16 + quad * 4 + r;
        const int mg = m0 + ml;
        const float d1v = (mg < 960) ? (float)p.d1b[(size_t)ig * 960 + mg] : 0.0f;
        bounce[nl * 136 + ml] = (bf16)(acc[mt][nt][r] * d1v);
      }
  }
  __syncthreads();
  const int r2 = tid >> 1, half16 = tid & 1;
  const int chLim = (mt8 == 7) ? 8 : 16;   // cols >=960 never read (B2 K=960)
#pragma unroll
  for (int c = 0; c < 8; ++c) {
    const int ch16 = half16 * 8 + c;
    if (ch16 < chLim) {
      bf16x8 v = *(const bf16x8*)(bounce + r2 * 136 + ch16 * 8);
      *(bf16x8*)(p.Upr + (size_t)(n0 + r2) * 1024 + m0 + ch16 * 8) = v;
    }
  }
}

// B2 (trace reduce) fused with g0 for the NEXT chunk (independent work).
__global__ __launch_bounds__(256, 4) void kt_b2g0(TArgs p, int nB2,
                                                  bf16* G0n, const bf16* gw0b,
                                                  const bf16* d0b, int i0n, int chn) {
  __shared__ __align__(16) char lds[34816];
  __shared__ float red4[4];
  const int tid = threadIdx.x;
  const int idx = blockIdx.x;

  if (idx >= nB2) {   // g0 tail blocks (offset nB2 ≡ 0 mod 8 keeps XCD phase)
    if (chn > 0) g0_body(G0n, gw0b, d0b, i0n, chn, idx - nB2, tid);
    return;
  }

  const int mt8 = (idx >> 3) & 7;
  const int nb  = ((idx >> 6) << 3) + (idx & 7);
  if (nb >= p.ch || mt8 == 7) return;      // B2 has 7 m-tiles (M=896)

  bf16* As = (bf16*)lds;
  bf16* Bs = As + 8192;

  const int wid  = tid >> 6, lane = tid & 63;
  const int wm   = wid & 1, wn = wid >> 1;
  const int quad = lane >> 4, l16 = lane & 15;
  const int sr8  = lane >> 3, cph = lane & 7;
  const int m0   = mt8 * 128;
  const int ig   = p.i0 + nb;
  const int n0   = nb * 128;

  floatx4 acc[4][4];
#pragma unroll
  for (int a = 0; a < 4; ++a)
#pragma unroll
    for (int b = 0; b < 4; ++b)
#pragma unroll
      for (int r = 0; r < 4; ++r) acc[a][b][r] = 0.0f;

  for (int kc = 0; kc < p.K; kc += 64) {
    stage_async(p.A, m0, 1024, kc, As, wid, sr8, cph);
    stage_async(p.B, n0, 1024, kc, Bs, wid, sr8, cph);
    __syncthreads();
    mfma_block(As, Bs, acc, wm, wn, l16, quad);
    __syncthreads();
  }

  float s = 0.0f;
#pragma unroll
  for (int nt = 0; nt < 4; ++nt) {
    const int d = wn * 64 + nt * 16 + l16;
    if (d < 127) {
#pragma unroll
      for (int mt = 0; mt < 4; ++mt)
#pragma unroll
        for (int r = 0; r < 4; ++r) {
          const int mg = m0 + wm * 64 + mt * 16 + quad * 4 + r;  // < 896
          const float w = (float)p.d2b[(size_t)ig * 896 + mg] * p.gdw[mg * 128 + d];
          s += acc[mt][nt][r] * w;
        }
    }
  }
#pragma unroll
  for (int off = 1; off < 64; off <<= 1) s += __shfl_xor(s, off, 64);
  if (lane == 0) red4[wid] = s;
  __syncthreads();
  if (tid == 0) atomicAdd(p.tr + ig, red4[0] + red4[1] + red4[2] + red4[3]);
}

// ---------------- forward GEMMs (flattened grid, fusable) ----------------
struct FArgs {
  const bf16* A; int lda;
  const bf16* Bt; int ldb;
  const float* bias;
  bf16* C; int ldc;
  bf16* D; int ldd;
  float* outF; int ldo;
  int K; int realN; int gridX;
};

template <int ACT>
__device__ inline void fwd_body(const FArgs& p, int bx, bf16* As, bf16* Bs) {
  const int tid  = threadIdx.x;
  const int wid  = tid >> 6, lane = tid & 63;
  const int wm   = wid & 1, wn = wid >> 1;
  const int quad = lane >> 4, l16 = lane & 15;
  const int sr8  = lane >> 3, cph = lane & 7;
  const int m0   = (bx % p.gridX) * 128;
  const int bn0  = (bx / p.gridX) * 128;

  floatx4 acc[4][4];
#pragma unroll
  for (int a = 0; a < 4; ++a)
#pragma unroll
    for (int b = 0; b < 4; ++b)
#pragma unroll
      for (int r = 0; r < 4; ++r) acc[a][b][r] = 0.0f;

  for (int kc = 0; kc < p.K; kc += 64) {
    stage_async(p.A, m0, p.lda, kc, As, wid, sr8, cph);
    stage_async(p.Bt, bn0, p.ldb, kc, Bs, wid, sr8, cph);
    __syncthreads();
    mfma_block(As, Bs, acc, wm, wn, l16, quad);
    __syncthreads();
  }

#pragma unroll
  for (int nt = 0; nt < 4; ++nt) {
    const int ng = bn0 + wn * 64 + nt * 16 + l16;
    const float bv = (ng < p.realN) ? p.bias[ng] : 0.0f;
#pragma unroll
    for (int mt = 0; mt < 4; ++mt)
#pragma unroll
      for (int r = 0; r < 4; ++r) {
        const int i = m0 + wm * 64 + mt * 16 + quad * 4 + r;
        const float v = acc[mt][nt][r] + bv;
        if (ACT) {
          const float t = tanhf(v);
          p.C[(size_t)i * p.ldc + ng] = (ng < p.realN) ? (bf16)t : (bf16)0.0f;
          if (p.D && ng < p.realN)
            p.D[(size_t)i * p.ldd + ng] = (bf16)(1.0f - t * t);
        } else if (ng < p.realN) {
          p.outF[(size_t)i * p.ldo + ng] = v;
        }
      }
  }
}

// two tanh-GEMMs in one dispatch (e.g. L0 ∪ e0, L1 ∪ e1)
__global__ __launch_bounds__(256) void kt_fwd2(FArgs a, int na, FArgs b) {
  __shared__ __align__(16) bf16 As[8192];
  __shared__ __align__(16) bf16 Bs[8192];
  const int bx = blockIdx.x;
  if (bx < na) fwd_body<1>(a, bx, As, Bs);
  else         fwd_body<1>(b, bx - na, As, Bs);
}

// L2 ∪ g0(chunk0)
__global__ __launch_bounds__(256) void kt_l2g0(FArgs a, int na, bf16* G0,
                                               const bf16* gw0b, const bf16* d0b,
                                               int i0, int ch) {
  __shared__ __align__(16) bf16 As[8192];
  __shared__ __align__(16) bf16 Bs[8192];
  const int bx = blockIdx.x;
  if (bx < na) fwd_body<1>(a, bx, As, Bs);
  else         g0_body(G0, gw0b, d0b, i0, ch, bx - na, threadIdx.x);
}

// dx ∪ gdot
__global__ __launch_bounds__(256) void kt_dxgdot(FArgs a, int na,
                                                 const bf16* e1b, const float* bdw,
                                                 const float* bdb, float* gf,
                                                 float* gout) {
  __shared__ __align__(16) bf16 As[8192];
  __shared__ __align__(16) bf16 Bs[8192];
  const int bx = blockIdx.x;
  if (bx < na) { fwd_body<0>(a, bx, As, Bs); return; }
  const int i = (bx - na) * 4 + (threadIdx.x >> 6);
  const int lane = threadIdx.x & 63;
  float s = 0.0f;
  for (int k = lane; k < 448; k += 64) s += (float)e1b[(size_t)i * 512 + k] * bdw[k];
#pragma unroll
  for (int off = 32; off > 0; off >>= 1) s += __shfl_down(s, off, 64);
  if (lane == 0) {
    const float v = s + bdb[0];
    gf[i] = v;
    gout[i] = v;
  }
}

// ---------------- fused prep with LDS-tiled transposes ----------------
struct PArgs {
  const float *gw0, *gw1, *gw2, *gdw, *bw0, *bw1, *pt, *x;
  bf16 *gw0b, *gw0t, *gw1t, *gw2t, *gdwt, *bw0t, *bw1t, *Xg, *Xb;
};

__device__ inline void tpose_tile(bf16* dst, const float* src, int R, int C,
                                  int ldd, int tile, int tilesX, float* tl,
                                  int tid) {
  const int r0 = (tile % tilesX) * 64;
  const int c0 = (tile / tilesX) * 64;
  const int tx = tid & 63, ty0 = tid >> 6;
#pragma unroll
  for (int i = 0; i < 16; ++i) {
    const int ty = ty0 + i * 4;
    const int r = r0 + ty, c = c0 + tx;
    tl[ty * 65 + tx] = (r < R && c < C) ? src[(size_t)r * C + c] : 0.0f;
  }
  __syncthreads();
#pragma unroll
  for (int i = 0; i < 16; ++i) {
    const int ty = ty0 + i * 4;
    dst[(size_t)(c0 + ty) * ldd + r0 + tx] = (bf16)tl[tx * 65 + ty];
  }
}

__global__ __launch_bounds__(256) void kt_prep(PArgs p) {
  __shared__ float tl[64 * 65];
  int b = blockIdx.x;
  const int t = threadIdx.x;
  if (b < 512) { p.gw0b[b * 256 + t] = (bf16)p.gw0[b * 256 + t]; return; }
  b -= 512;
  if (b < 768) {  // build Xg/Xb
    const int idx = b * 256 + t;
    const int i = idx / 192, c = idx % 192;
    const float s = p.pt[0];
    float vb;
    if (c == 0) vb = s;
    else if (c <= 128) vb = p.x[i * 128 + c - 1];
    else vb = 0.0f;
    p.Xb[i * 192 + c] = (bf16)vb;
    if (c < 128) p.Xg[i * 128 + c] = (bf16)((c == 0) ? s : p.x[i * 128 + c - 1]);
    return;
  }
  b -= 768;
  if (b < 32)  { tpose_tile(p.gw0t, p.gw0, 128, 1024, 128, b, 2, tl, t);  return; }
  b -= 32;
  if (b < 256) { tpose_tile(p.gw1t, p.gw1, 1024, 960, 1024, b, 16, tl, t); return; }
  b -= 256;
  if (b < 256) { tpose_tile(p.gw2t, p.gw2, 960, 896, 1024, b, 16, tl, t); return; }
  b -= 256;
  if (b < 32)  { tpose_tile(p.gdwt, p.gdw, 896, 128, 1024, b, 16, tl, t); return; }
  b -= 32;
  if (b < 24)  { tpose_tile(p.bw0t, p.bw0, 129, 512, 192, b, 3, tl, t);  return; }
  b -= 24;
  if (b < 64)  { tpose_tile(p.bw1t, p.bw1, 512, 448, 512, b, 8, tl, t);  return; }
}

__global__ __launch_bounds__(256) void kt_fin(const float* gf, const float* tr,
                                              const float* pp, float* dp) {
  const int i = blockIdx.x * 256 + threadIdx.x;
  if (i < 1024) dp[i] = gf[i] - pp[i] * tr[i];
}

extern "C" void kernel_launch(void* const* d_in, const int* in_sizes, int n_in,
                              void* d_out, int out_size, void* d_ws, size_t ws_size,
                              hipStream_t stream) {
  const float* pt  = (const float*)d_in[0];
  const float* x   = (const float*)d_in[1];
  const float* pp  = (const float*)d_in[3];
  const float* gw0 = (const float*)d_in[4];
  const float* gb0 = (const float*)d_in[5];
  const float* gw1 = (const float*)d_in[6];
  const float* gb1 = (const float*)d_in[7];
  const float* gw2 = (const float*)d_in[8];
  const float* gb2 = (const float*)d_in[9];
  const float* gdw = (const float*)d_in[10];
  const float* gdb = (const float*)d_in[11];
  const float* bw0 = (const float*)d_in[12];
  const float* bb0 = (const float*)d_in[13];
  const float* bw1 = (const float*)d_in[14];
  const float* bb1 = (const float*)d_in[15];
  const float* bdw = (const float*)d_in[16];
  const float* bdb = (const float*)d_in[17];
  float* out = (float*)d_out;

  char* w = (char*)d_ws;
  size_t used = 0;
  auto alloc = [&](size_t nbytes) -> void* {
    void* r = w + used;
    used += (nbytes + 255) & ~(size_t)255;
    return r;
  };
  bf16* gw0b = (bf16*)alloc((size_t)128 * 1024 * 2);
  bf16* gw0t = (bf16*)alloc((size_t)1024 * 128 * 2);
  bf16* gw1t = (bf16*)alloc((size_t)1024 * 1024 * 2);
  bf16* gw2t = (bf16*)alloc((size_t)1024 * 1024 * 2);
  bf16* gdwt = (bf16*)alloc((size_t)128 * 1024 * 2);
  bf16* bw0t = (bf16*)alloc((size_t)512 * 192 * 2);
  bf16* bw1t = (bf16*)alloc((size_t)512 * 512 * 2);
  bf16* Xg   = (bf16*)alloc((size_t)1024 * 128 * 2);
  bf16* Xb   = (bf16*)alloc((size_t)1024 * 192 * 2);
  bf16* h0b  = (bf16*)alloc((size_t)1024 * 1024 * 2);
  bf16* h1b  = (bf16*)alloc((size_t)1024 * 1024 * 2);
  bf16* h2b  = (bf16*)alloc((size_t)1024 * 1024 * 2);
  bf16* e0b  = (bf16*)alloc((size_t)1024 * 512 * 2);
  bf16* e1b  = (bf16*)alloc((size_t)1024 * 512 * 2);
  bf16* d0b  = (bf16*)alloc((size_t)1024 * 1024 * 2);
  bf16* d1b  = (bf16*)alloc((size_t)1024 * 960 * 2);
  bf16* d2b  = (bf16*)alloc((size_t)1024 * 896 * 2);
  float* gf  = (float*)alloc(1024 * 4);
  float* tr  = (float*)alloc(1024 * 4);

  const size_t perSample = (size_t)128 * 1024 * 2;     // 256 KB
  size_t avail = (ws_size > used) ? ws_size - used : 0;
  int CH = (int)(avail / (2 * perSample));
  if (CH > 256) CH = 256;   // 4 chunks; G0+Upr = 128 MB stays L3-resident
  if (CH < 1) CH = 1;
  bf16* G0  = (bf16*)alloc((size_t)CH * perSample);
  bf16* Upr = (bf16*)(w + used);

  hipMemsetAsync(tr, 0, 1024 * 4, stream);

  {
    PArgs a{gw0, gw1, gw2, gdw, bw0, bw1, pt, x,
            gw0b, gw0t, gw1t, gw2t, gdwt, bw0t, bw1t, Xg, Xb};
    kt_prep<<<dim3(1944), 256, 0, stream>>>(a);
  }

  // F1 = L0 ∪ e0
  {
    FArgs a{}; a.A = Xg; a.lda = 128; a.Bt = gw0t; a.ldb = 128; a.bias = gb0;
    a.C = h0b; a.ldc = 1024; a.D = d0b; a.ldd = 1024; a.K = 128; a.realN = 1024;
    a.gridX = 8;   // 64 blocks
    FArgs b{}; b.A = Xb; b.lda = 192; b.Bt = bw0t; b.ldb = 192; b.bias = bb0;
    b.C = e0b; b.ldc = 512; b.K = 192; b.realN = 512; b.gridX = 8;  // 32 blocks
    kt_fwd2<<<dim3(96), 256, 0, stream>>>(a, 64, b);
  }
  // F2 = L1 ∪ e1
  {
    FArgs a{}; a.A = h0b; a.lda = 1024; a.Bt = gw1t; a.ldb = 1024; a.bias = gb1;
    a.C = h1b; a.ldc = 1024; a.D = d1b; a.ldd = 960; a.K = 1024; a.realN = 960;
    a.gridX = 8;   // 64 blocks
    FArgs b{}; b.A = e0b; b.lda = 512; b.Bt = bw1t; b.ldb = 512; b.bias = bb1;
    b.C = e1b; b.ldc = 512; b.K = 512; b.realN = 448; b.gridX = 8;  // 32 blocks
    kt_fwd2<<<dim3(96), 256, 0, stream>>>(a, 64, b);
  }
  // F3 = L2 ∪ g0(chunk 0)
  const int ch0  = (1024 < CH) ? 1024 : CH;
  const int ch08 = (ch0 + 7) & ~7;
  {
    FArgs a{}; a.A = h1b; a.lda = 1024; a.Bt = gw2t; a.ldb = 1024; a.bias = gb2;
    a.C = h2b; a.ldc = 1024; a.D = d2b; a.ldd = 896; a.K = 1024; a.realN = 896;
    a.gridX = 8;   // 56 blocks (offset 56 ≡ 0 mod 8 keeps g0's XCD phase)
    kt_l2g0<<<dim3(56 + ch08 * 64), 256, 0, stream>>>(a, 56, G0, gw0b, d0b, 0, ch0);
  }
  // F4 = dx ∪ gdot
  {
    FArgs a{}; a.A = h2b; a.lda = 1024; a.Bt = gdwt; a.ldb = 1024; a.bias = gdb;
    a.outF = out; a.ldo = 128; a.K = 896; a.realN = 128; a.gridX = 8;  // 8 blocks
    kt_dxgdot<<<dim3(8 + 256), 256, 0, stream>>>(a, 8, e1b, bdw, bdb, gf, out + 131072);
  }

  for (int i0 = 0; i0 < 1024; i0 += CH) {
    const int ch  = (1024 - i0 < CH) ? (1024 - i0) : CH;
    const int ch8 = (ch + 7) & ~7;
    {  // B1: U' = D1 * (gw1^T @ G0), M pad 1024, K=1024
      TArgs a{}; a.A = gw1t; a.B = G0; a.d1b = d1b; a.Upr = Upr; a.i0 = i0;
      a.K = 1024; a.ch = ch;
      kt_b1<<<dim3(8 * ch8), 256, 0, stream>>>(a);
    }
    {  // B2 ∪ g0(next chunk)
      const int i0n = i0 + CH;
      const int chn = (i0n < 1024) ? ((1024 - i0n < CH) ? (1024 - i0n) : CH) : 0;
      const int chn8 = (chn + 7) & ~7;
      TArgs a{}; a.A = gw2t; a.B = Upr; a.d2b = d2b; a.gdw = gdw; a.tr = tr;
      a.i0 = i0; a.K = 960; a.ch = ch;
      kt_b2g0<<<dim3(8 * ch8 + chn8 * 64), 256, 0, stream>>>(
          a, 8 * ch8, G0, gw0b, d0b, i0n, chn);
    }
  }

  kt_fin<<<dim3(4), 256, 0, stream>>>(gf, tr, pp, out + 132096);
}